// Round 13
// baseline (235.411 us; speedup 1.0000x reference)
//
#include <hip/hip_runtime.h>
#include <math.h>

#define BATCH 64
#define CIN   256
#define HH    56
#define WW    56
#define HW    (HH*WW)      // 3136
#define WIDTH 64
#define COUT  256
#define K_CH  32
#define K_SP  1568
#define EPS   1e-5f

typedef short short8 __attribute__((ext_vector_type(8)));
typedef float f32x4 __attribute__((ext_vector_type(4)));

#define MFMA16(a, b, c) __builtin_amdgcn_mfma_f32_16x16x32_bf16((a), (b), (c), 0, 0, 0)

__device__ __forceinline__ unsigned short f2bf(float f) {
    unsigned u = __builtin_bit_cast(unsigned, f);
    u += 0x7fffu + ((u >> 16) & 1u);
    return (unsigned short)(u >> 16);
}

// ---------------- Kernel 1: FUSED pool + spatial-saliency + conv1(64oc, unmasked) — ONE x pass ----------------
// grid (7, BATCH), 256 thr = 4 waves; wave w: px = p0 + w*112 + ln + nt*16 (7 n-tiles), 64 oc.
// Per lane per (ks,nt): 8 f32 x-loads feed (a) bf16 MFMA fragment, (b) 8 f64 FMAs for spsal
// partial (register), (c) 8 f64 adds for channel partials (LDS tree-reduced per ks, fixed order).
// No kidx/mdil dependency: out1h is relu(bn1(conv1 x)) for ALL 64 oc; masks applied at conv2 stage.
__global__ __launch_bounds__(256, 2) void k_fused1(const float* __restrict__ x,
                                                   const float* __restrict__ w1,
                                                   const float* __restrict__ g1, const float* __restrict__ b1,
                                                   const float* __restrict__ m1, const float* __restrict__ v1,
                                                   const float* __restrict__ mask_w,
                                                   short* __restrict__ out1h,
                                                   double* __restrict__ spsal,
                                                   double* __restrict__ pooled_part) {
    __shared__ float scc[64], shc[64];
    __shared__ float wsh[256];
    __shared__ double pl[32][65];     // 16.6 KB
    int b = blockIdx.y, chunk = blockIdx.x, p0 = chunk * 448;
    int tid = threadIdx.x, w = tid >> 6, lane = tid & 63, g = lane >> 4, ln = lane & 15;
    if (tid < 64) {
        float s = g1[tid] * rsqrtf(v1[tid] + EPS);
        scc[tid] = s; shc[tid] = b1[tid] - m1[tid] * s;
    }
    wsh[tid] = mask_w[tid];
    __syncthreads();

    int pxw = p0 + w * 112 + ln;
    f32x4 acc[4][7];
    f32x4 zz = {0.f, 0.f, 0.f, 0.f};
#pragma unroll
    for (int m = 0; m < 4; m++)
#pragma unroll
        for (int nt = 0; nt < 7; nt++) acc[m][nt] = zz;
    double sp[7];
#pragma unroll
    for (int nt = 0; nt < 7; nt++) sp[nt] = 0.0;

#pragma clang loop unroll(disable)
    for (int ks = 0; ks < 8; ks++) {
        // weight fragments for 4 m-tiles, f32 -> bf16 on the fly
        short8 afr[4];
#pragma unroll
        for (int m = 0; m < 4; m++) {
            const float* wp = w1 + ((m * 16 + ln) * 256 + ks * 32 + g * 8);
            f32x4 a0 = *(const f32x4*)(wp);
            f32x4 a1 = *(const f32x4*)(wp + 4);
#pragma unroll
            for (int j = 0; j < 4; j++) {
                afr[m][j]     = (short)f2bf(a0[j]);
                afr[m][4 + j] = (short)f2bf(a1[j]);
            }
        }
        float wc[8];
#pragma unroll
        for (int j = 0; j < 8; j++) wc[j] = wsh[ks * 32 + g * 8 + j];
        double pc[8];
#pragma unroll
        for (int j = 0; j < 8; j++) pc[j] = 0.0;

        const float* xp0 = x + ((size_t)(b * 256 + ks * 32 + g * 8)) * HW + pxw;
#pragma unroll
        for (int nt = 0; nt < 7; nt++) {
            const float* xp = xp0 + nt * 16;
            float xv[8];
#pragma unroll
            for (int j = 0; j < 8; j++) xv[j] = xp[(size_t)j * HW];
            short8 bfr;
            double s = 0.0;
#pragma unroll
            for (int j = 0; j < 8; j++) {
                bfr[j] = (short)f2bf(xv[j]);
                double d = (double)xv[j];
                s += d * (double)wc[j];
                pc[j] += d;
            }
            sp[nt] += s;
#pragma unroll
            for (int m = 0; m < 4; m++) acc[m][nt] = MFMA16(afr[m], bfr, acc[m][nt]);
        }
        // flush + tree-reduce the 32 channel partials of this ks group (fixed order)
        __syncthreads();
#pragma unroll
        for (int j = 0; j < 8; j++) pl[g * 8 + j][w * 16 + ln] = pc[j];
        __syncthreads();
        for (int off = 32; off > 0; off >>= 1) {
            for (int k2 = tid; k2 < 32 * off; k2 += 256) {
                int ch = k2 / off, i2 = k2 - ch * off;
                pl[ch][i2] += pl[ch][i2 + off];
            }
            __syncthreads();
        }
        if (tid < 32)
            pooled_part[((size_t)(b * 7 + chunk)) * 256 + ks * 32 + tid] = pl[tid][0];
    }

    // spsal: combine the 4 g-groups (same px) via xor-shuffle, deterministic
#pragma unroll
    for (int nt = 0; nt < 7; nt++) {
        double s = sp[nt];
        s += __shfl_xor(s, 16, 64);
        s += __shfl_xor(s, 32, 64);
        if (g == 0) spsal[(size_t)b * HW + pxw + nt * 16] = s;
    }

    // conv1 epilogue: relu(bn1) for all 64 oc, UNMASKED
#pragma unroll
    for (int nt = 0; nt < 7; nt++) {
        int px = pxw + nt * 16;
#pragma unroll
        for (int m = 0; m < 4; m++) {
            int oc = m * 16 + g * 4;
            float y0 = fmaxf(acc[m][nt][0] * scc[oc + 0] + shc[oc + 0], 0.f);
            float y1 = fmaxf(acc[m][nt][1] * scc[oc + 1] + shc[oc + 1], 0.f);
            float y2 = fmaxf(acc[m][nt][2] * scc[oc + 2] + shc[oc + 2], 0.f);
            float y3 = fmaxf(acc[m][nt][3] * scc[oc + 3] + shc[oc + 3], 0.f);
            uint2 u;
            u.x = (unsigned)f2bf(y0) | ((unsigned)f2bf(y1) << 16);
            u.y = (unsigned)f2bf(y2) | ((unsigned)f2bf(y3) << 16);
            *(uint2*)(out1h + ((size_t)(b * HW + px)) * 64 + m * 16 + g * 4) = u;
        }
    }
}

// ---------------- Kernel 2: FUSED selection — spmask (blocks 0-63) + changather (blocks 64-127) ----------------
__global__ __launch_bounds__(256) void k_sel(const double* __restrict__ pooled_part,
                                             const float* __restrict__ fc_w,
                                             const float* __restrict__ fc_b,
                                             const float* __restrict__ w2,
                                             const float* __restrict__ w3,
                                             const double* __restrict__ spsal,
                                             int* __restrict__ kidx,
                                             unsigned short* __restrict__ kmask,
                                             short* __restrict__ wt2c,
                                             short* __restrict__ w3c,
                                             float* __restrict__ mask,
                                             float* __restrict__ mdil) {
    int role = blockIdx.x >> 6;
    int b = blockIdx.x & 63;
    int tid = threadIdx.x;

    __shared__ unsigned long long ks[HW];
    __shared__ float m[HW];
    __shared__ unsigned int hist[256];
    __shared__ unsigned int sc[256];
    __shared__ unsigned long long sh_prefix;
    __shared__ unsigned int sh_krem;
    __shared__ double ps[CIN];
    __shared__ double ss[WIDTH];
    __shared__ double kth;
    __shared__ int ki[K_CH];

    if (role == 1) {
        for (int i = tid; i < CIN; i += 256) {
            double s = 0.0;
            for (int k = 0; k < 7; k++) s += pooled_part[((size_t)(b * 7 + k)) * 256 + i];
            ps[i] = s * (1.0 / (double)HW);
        }
        __syncthreads();
        if (tid < 64) {
            double acc = (double)fc_b[tid];
            const float* wr = fc_w + tid * CIN;
            for (int k = 0; k < CIN; k++) acc += ps[k] * (double)wr[k];
            ss[tid] = 1.0 / (1.0 + exp(-acc));
        }
        __syncthreads();
        if (tid < 64) {
            double sal = ss[tid];
            int cg = 0, ce = 0;
            for (int i = 0; i < WIDTH; i++) {
                cg += (ss[i] > sal);
                ce += (ss[i] == sal);
            }
            if (cg <= K_CH - 1 && cg + ce >= K_CH) kth = sal;
        }
        __syncthreads();
        if (tid < 64) {
            double sal = ss[tid];
            int kept = (sal >= kth) ? 1 : 0;
            kmask[b * WIDTH + tid] = kept ? 0xFFFFu : 0u;
            int pos = 0;
            for (int i = 0; i < tid; i++) pos += (ss[i] >= kth) ? 1 : 0;
            if (kept && pos < K_CH) { kidx[b * K_CH + pos] = tid; ki[pos] = tid; }
        }
        __syncthreads();
        // wt2c[b][tap][oc_c 32][c 64] — oc compacted, input channels FULL (masking via AND at stage)
        for (int i = tid; i < 18432; i += 256) {
            int tap = i >> 11, rem = i & 2047;
            int oc_c = rem >> 6, c = rem & 63;
            wt2c[(size_t)b * 18432 + i] = (short)f2bf(w2[ki[oc_c] * 576 + c * 9 + tap]);
        }
        for (int i = tid; i < 8192; i += 256) {
            int oc = i >> 5, c_c = i & 31;
            w3c[(size_t)b * 8192 + i] = (short)f2bf(w3[oc * 64 + ki[c_c]]);
        }
        return;
    }

    // ----- spatial kth via EXACT 64-bit radix-select + mask + 3x3 dilate -----
#pragma unroll
    for (int i = 0; i < 13; i++) {
        int px = i * 256 + tid;
        if (px < HW) {
            double s = spsal[(size_t)b * HW + px];
            unsigned long long u = __builtin_bit_cast(unsigned long long, s);
            ks[px] = (u >> 63) ? ~u : (u | 0x8000000000000000ULL);
        }
    }
    if (tid == 0) { sh_prefix = 0ULL; sh_krem = K_SP; }
    __syncthreads();

    unsigned long long pmask = 0ULL;
    for (int pass = 0; pass < 8; pass++) {
        int shift = 56 - 8 * pass;
        hist[tid] = 0;
        __syncthreads();
        unsigned long long prefix = sh_prefix;
#pragma unroll
        for (int i = 0; i < 13; i++) {
            int px = i * 256 + tid;
            if (px < HW) {
                unsigned long long k = ks[px];
                if ((k & pmask) == prefix)
                    atomicAdd(&hist[(unsigned)((k >> shift) & 255ULL)], 1u);
            }
        }
        __syncthreads();
        sc[tid] = hist[255 - tid];
        __syncthreads();
        for (int off = 1; off < 256; off <<= 1) {
            unsigned v = sc[tid];
            unsigned a = (tid >= off) ? sc[tid - off] : 0u;
            __syncthreads();
            sc[tid] = v + a;
            __syncthreads();
        }
        unsigned krem = sh_krem;
        unsigned cum = sc[tid];
        unsigned cumHigher = (tid > 0) ? sc[tid - 1] : 0u;
        __syncthreads();
        if (cum >= krem && cumHigher < krem) {
            int d = 255 - tid;
            sh_krem = krem - cumHigher;
            sh_prefix = prefix | ((unsigned long long)d << shift);
        }
        pmask |= (0xFFULL << shift);
        __syncthreads();
    }
    unsigned long long kthk = sh_prefix;

#pragma unroll
    for (int i = 0; i < 13; i++) {
        int px = i * 256 + tid;
        if (px < HW) {
            float mv = (ks[px] >= kthk) ? 1.0f : 0.0f;
            m[px] = mv;
            mask[b * HW + px] = mv;
        }
    }
    __syncthreads();
    for (int p = tid; p < HW; p += 256) {
        int y = p / WW, xx = p % WW;
        float mx = 0.0f;
        for (int dy = -1; dy <= 1; dy++) {
            int yy = y + dy;
            if (yy < 0 || yy >= HH) continue;
            for (int dx = -1; dx <= 1; dx++) {
                int xc = xx + dx;
                if (xc < 0 || xc >= WW) continue;
                mx = fmaxf(mx, m[yy * WW + xc]);
            }
        }
        mdil[b * HW + p] = mx;
    }
}

// ---------------- Kernel 6: conv2 3x3 (64 masked -> 32 kept), 4-row tiles / 128 thr ----------------
// Staging applies mdil(px) AND kmask(c) as bitwise AND (both exactly 0/1, relu input >= 0 — exact).
__global__ __launch_bounds__(128, 2) void k_conv2(const short* __restrict__ out1h,
                                                  const short* __restrict__ wt2c,
                                                  const float* __restrict__ g2, const float* __restrict__ b2,
                                                  const float* __restrict__ m2, const float* __restrict__ v2,
                                                  const float* __restrict__ mask,
                                                  const float* __restrict__ mdil,
                                                  const int* __restrict__ kidx,
                                                  const unsigned short* __restrict__ kmask,
                                                  short* __restrict__ out2c) {
    __shared__ short lds[6 * 58 * 64];   // 44544 B
    __shared__ float scc[32], shc[32];
    __shared__ unsigned short kms[64];
    int b = blockIdx.y, r0 = blockIdx.x * 4, p0 = r0 * 56;
    int tid = threadIdx.x, w = tid >> 6, lane = tid & 63, g = lane >> 4, ln = lane & 15;
    if (tid < 32) {
        int c = kidx[b * K_CH + tid];
        float s = g2[c] * rsqrtf(v2[c] + EPS);
        scc[tid] = s; shc[tid] = b2[c] - m2[c] * s;
    }
    if (tid < 64) kms[tid] = kmask[b * WIDTH + tid];
    __syncthreads();
    short8 z8 = {0, 0, 0, 0, 0, 0, 0, 0};
    for (int i = tid; i < 2784; i += 128) {      // 6*58*8 chunks of 8 shorts
        int cblk = i & 7;
        int colr = i >> 3;
        int col = colr % 58, ri = colr / 58;
        int gr = r0 - 1 + ri, gc = col - 1;
        short8 v8 = z8;
        if (gr >= 0 && gr < HH && gc >= 0 && gc < WW) {
            int gpx = b * HW + gr * WW + gc;
            v8 = *(const short8*)(out1h + ((size_t)gpx) * 64 + cblk * 8);
            unsigned short mm = (mdil[gpx] != 0.0f) ? 0xFFFFu : 0u;
            short8 km = *(const short8*)(&kms[cblk * 8]);
#pragma unroll
            for (int j = 0; j < 8; j++)
                v8[j] = (short)(v8[j] & km[j] & (short)mm);
        }
        *(short8*)(&lds[(ri * 58 + col) * 64 + ((cblk * 8) ^ ((col & 7) << 3))]) = v8;
    }
    __syncthreads();

    f32x4 acc[2][7];
    f32x4 zz = {0.f, 0.f, 0.f, 0.f};
#pragma unroll
    for (int m = 0; m < 2; m++)
#pragma unroll
        for (int nt = 0; nt < 7; nt++) acc[m][nt] = zz;

    const short* wtb = wt2c + (size_t)b * 18432;
    int prel0 = w * 112 + ln;
    for (int tap = 0; tap < 9; tap++) {
        int dy = tap / 3 - 1;
        int dx = tap - (tap / 3) * 3 - 1;
        short8 afr[2][2];
#pragma unroll
        for (int m = 0; m < 2; m++)
#pragma unroll
            for (int ks2 = 0; ks2 < 2; ks2++)
                afr[m][ks2] = *(const short8*)(wtb + tap * 2048 + (m * 16 + ln) * 64 + ks2 * 32 + g * 8);
#pragma unroll
        for (int nt = 0; nt < 7; nt++) {
            int prel = prel0 + nt * 16;
            int rrel = prel / 56;
            int xcol = prel - rrel * 56;
            int row_l = rrel + 1 + dy;
            int col_l = xcol + 1 + dx;
            int base = (row_l * 58 + col_l) * 64;
            int sw = (col_l & 7) << 3;
#pragma unroll
            for (int ks2 = 0; ks2 < 2; ks2++) {
                short8 bfr = *(const short8*)(&lds[base + ((ks2 * 32 + g * 8) ^ sw)]);
#pragma unroll
                for (int m = 0; m < 2; m++) acc[m][nt] = MFMA16(afr[m][ks2], bfr, acc[m][nt]);
            }
        }
    }
#pragma unroll
    for (int nt = 0; nt < 7; nt++) {
        int px = p0 + prel0 + nt * 16;
        float mv = mask[b * HW + px];
#pragma unroll
        for (int m = 0; m < 2; m++) {
            int oc = m * 16 + g * 4;
            float y0 = fmaxf(acc[m][nt][0] * scc[oc + 0] + shc[oc + 0], 0.f) * mv;
            float y1 = fmaxf(acc[m][nt][1] * scc[oc + 1] + shc[oc + 1], 0.f) * mv;
            float y2 = fmaxf(acc[m][nt][2] * scc[oc + 2] + shc[oc + 2], 0.f) * mv;
            float y3 = fmaxf(acc[m][nt][3] * scc[oc + 3] + shc[oc + 3], 0.f) * mv;
            uint2 u;
            u.x = (unsigned)f2bf(y0) | ((unsigned)f2bf(y1) << 16);
            u.y = (unsigned)f2bf(y2) | ((unsigned)f2bf(y3) << 16);
            *(uint2*)(out2c + ((size_t)(b * HW + px)) * 32 + oc) = u;
        }
    }
}

// ---------------- Kernel 7: conv3 1x1 (32 kept ->256), 16-oc waves for 4 waves/SIMD occupancy ----------------
__global__ __launch_bounds__(256, 4) void k_conv3(const short* __restrict__ out2c,
                                                  const short* __restrict__ w3c,
                                                  const float* __restrict__ g3, const float* __restrict__ b3,
                                                  const float* __restrict__ m3, const float* __restrict__ v3,
                                                  const float* __restrict__ mask,
                                                  const float* __restrict__ x,
                                                  float* __restrict__ out) {
    int b = blockIdx.y;
    int ocb = blockIdx.x / 28;          // 0..3
    int pxb = blockIdx.x % 28;          // 0..27
    int p0 = pxb * 112;
    int tid = threadIdx.x, w = tid >> 6, lane = tid & 63, g = lane >> 4, ln = lane & 15;
    int oc0 = ocb * 64 + w * 16;
    int oc = oc0 + ln;

    const short* w3b = w3c + (size_t)b * 8192;
    short8 wfr = *(const short8*)(w3b + oc * 32 + g * 8);

    short8 act[7];
#pragma unroll
    for (int nt = 0; nt < 7; nt++)
        act[nt] = *(const short8*)(out2c + ((size_t)(b * HW + p0 + nt * 16 + ln)) * 32 + g * 8);

    f32x4 xr[7];
#pragma unroll
    for (int nt = 0; nt < 7; nt++) {
        int px0 = p0 + nt * 16 + g * 4;
        xr[nt] = *(const f32x4*)(x + ((size_t)(b * COUT + oc)) * HW + px0);
    }
    __builtin_amdgcn_sched_barrier(0);

    f32x4 acc[7];
    f32x4 zz = {0.f, 0.f, 0.f, 0.f};
#pragma unroll
    for (int nt = 0; nt < 7; nt++) acc[nt] = zz;
#pragma unroll
    for (int nt = 0; nt < 7; nt++)
        acc[nt] = MFMA16(act[nt], wfr, acc[nt]);

    float s_ = g3[oc] * rsqrtf(v3[oc] + EPS);
    float h_ = b3[oc] - m3[oc] * s_;
#pragma unroll
    for (int nt = 0; nt < 7; nt++) {
        int px0 = p0 + nt * 16 + g * 4;
        f32x4 mv = *(const f32x4*)(mask + (size_t)b * HW + px0);
        size_t idx = ((size_t)(b * COUT + oc)) * HW + px0;
        f32x4 o;
#pragma unroll
        for (int i = 0; i < 4; i++)
            o[i] = fmaxf(xr[nt][i] + (acc[nt][i] * s_ + h_) * mv[i], 0.f);
        *(f32x4*)(out + idx) = o;
    }
}

extern "C" void kernel_launch(void* const* d_in, const int* in_sizes, int n_in,
                              void* d_out, int out_size, void* d_ws, size_t ws_size,
                              hipStream_t stream) {
    const float* x       = (const float*)d_in[0];
    const float* conv1_w = (const float*)d_in[1];
    const float* bn1_g   = (const float*)d_in[2];
    const float* bn1_b   = (const float*)d_in[3];
    const float* bn1_m   = (const float*)d_in[4];
    const float* bn1_v   = (const float*)d_in[5];
    const float* conv2_w = (const float*)d_in[6];
    const float* bn2_g   = (const float*)d_in[7];
    const float* bn2_b   = (const float*)d_in[8];
    const float* bn2_m   = (const float*)d_in[9];
    const float* bn2_v   = (const float*)d_in[10];
    const float* conv3_w = (const float*)d_in[11];
    const float* bn3_g   = (const float*)d_in[12];
    const float* bn3_b   = (const float*)d_in[13];
    const float* bn3_m   = (const float*)d_in[14];
    const float* bn3_v   = (const float*)d_in[15];
    const float* fc_w    = (const float*)d_in[16];
    const float* fc_b    = (const float*)d_in[17];
    const float* mask_w  = (const float*)d_in[18];
    const float* mask_b  = (const float*)d_in[19];
    (void)mask_b;   // constant bias cancels in (sal >= kth)

    char* wsb = (char*)d_ws;
    size_t off = 0;
    double* pooled_part = (double*)(wsb + off); off += (size_t)BATCH * 7 * 256 * 8;   // 917 KB
    double* spsal  = (double*)(wsb + off); off += (size_t)BATCH * HW * 8;             // 1.6 MB
    float* mask    = (float*)(wsb + off);  off += (size_t)BATCH * HW * 4;
    float* mdil    = (float*)(wsb + off);  off += (size_t)BATCH * HW * 4;
    int*   kidx    = (int*)(wsb + off);    off += (size_t)BATCH * K_CH * 4;
    unsigned short* kmask = (unsigned short*)(wsb + off); off += (size_t)BATCH * WIDTH * 2;
    short* wt2c    = (short*)(wsb + off);  off += (size_t)BATCH * 18432 * 2;          // 2.36 MB
    short* w3c     = (short*)(wsb + off);  off += (size_t)BATCH * 8192 * 2;           // 1.05 MB
    short* out1h   = (short*)(wsb + off);  off += (size_t)BATCH * HW * 64 * 2;        // 25.7 MB
    short* out2c   = (short*)(wsb + off);  off += (size_t)BATCH * HW * 32 * 2;        // 12.8 MB
    (void)ws_size; (void)in_sizes; (void)n_in; (void)out_size;

    k_fused1<<<dim3(7, BATCH), 256, 0, stream>>>(x, conv1_w, bn1_g, bn1_b, bn1_m, bn1_v,
                                                 mask_w, out1h, spsal, pooled_part);
    k_sel<<<128, 256, 0, stream>>>(pooled_part, fc_w, fc_b, conv2_w, conv3_w, spsal,
                                   kidx, kmask, wt2c, w3c, mask, mdil);
    k_conv2<<<dim3(14, BATCH), 128, 0, stream>>>(out1h, wt2c, bn2_g, bn2_b, bn2_m, bn2_v,
                                                 mask, mdil, kidx, kmask, out2c);
    k_conv3<<<dim3(112, BATCH), 256, 0, stream>>>(out2c, w3c, bn3_g, bn3_b, bn3_m, bn3_v, mask, x, (float*)d_out);
}

// Round 14
// 211.598 us; speedup vs baseline: 1.1125x; 1.1125x over previous
//
#include <hip/hip_runtime.h>
#include <math.h>

#define BATCH 64
#define CIN   256
#define HH    56
#define WW    56
#define HW    (HH*WW)      // 3136
#define WIDTH 64
#define COUT  256
#define K_CH  32
#define K_SP  1568
#define EPS   1e-5f

typedef short short8 __attribute__((ext_vector_type(8)));
typedef float f32x4 __attribute__((ext_vector_type(4)));

#define MFMA16(a, b, c) __builtin_amdgcn_mfma_f32_16x16x32_bf16((a), (b), (c), 0, 0, 0)

__device__ __forceinline__ unsigned short f2bf(float f) {
    unsigned u = __builtin_bit_cast(unsigned, f);
    u += 0x7fffu + ((u >> 16) & 1u);
    return (unsigned short)(u >> 16);
}

// ---------------- Kernel 1: FUSED pool + spatial-saliency, float4 loads, liveness-controlled ----------------
__global__ __launch_bounds__(256) void k_poolsal(const float* __restrict__ x,
                                                 const float* __restrict__ mask_w,
                                                 double* __restrict__ pooled,
                                                 double* __restrict__ spart) {
    int ct = blockIdx.x, b = blockIdx.y;
    int tid = threadIdx.x;
    __shared__ double pl[16][257];
    double sp0[4], sp1[4], sp2[4], spt[4];
#pragma unroll
    for (int k = 0; k < 4; k++) { sp0[k] = 0.0; sp1[k] = 0.0; sp2[k] = 0.0; spt[k] = 0.0; }

#pragma clang loop unroll(disable)
    for (int c = 0; c < 16; c++) {
        const float* xr = x + ((size_t)(b * CIN + ct * 16 + c)) * HW;
        double w = (double)mask_w[ct * 16 + c];
        f32x4 v0 = *(const f32x4*)(xr + tid * 4);
        f32x4 v1 = *(const f32x4*)(xr + 1024 + tid * 4);
        f32x4 v2 = *(const f32x4*)(xr + 2048 + tid * 4);
        double s = 0.0;
#pragma unroll
        for (int k = 0; k < 4; k++) {
            double d0 = (double)v0[k], d1 = (double)v1[k], d2 = (double)v2[k];
            sp0[k] += d0 * w; sp1[k] += d1 * w; sp2[k] += d2 * w;
            s += d0 + d1 + d2;
        }
        if (tid < 16) {
            f32x4 v3 = *(const f32x4*)(xr + 3072 + tid * 4);
#pragma unroll
            for (int k = 0; k < 4; k++) {
                double d3 = (double)v3[k];
                spt[k] += d3 * w;
                s += d3;
            }
        }
        pl[c][tid] = s;
    }
    double* so = spart + ((size_t)(b * 16 + ct)) * HW;
#pragma unroll
    for (int k = 0; k < 4; k++) {
        so[tid * 4 + k] = sp0[k];
        so[1024 + tid * 4 + k] = sp1[k];
        so[2048 + tid * 4 + k] = sp2[k];
    }
    if (tid < 16) {
#pragma unroll
        for (int k = 0; k < 4; k++) so[3072 + tid * 4 + k] = spt[k];
    }
    __syncthreads();
    for (int off = 128; off > 0; off >>= 1) {
        for (int k = tid; k < 16 * off; k += 256) {
            int c = k / off, j = k - c * off;
            pl[c][j] += pl[c][j + off];
        }
        __syncthreads();
    }
    if (tid < 16) pooled[b * CIN + ct * 16 + tid] = pl[tid][0] * (1.0 / (double)HW);
}

// ---------------- Kernel 2: FUSED selection — spmask (blocks 0-63) + changather (blocks 64-127) ----------------
// Radix-select scan done as wave-level __shfl_up scan (5 barriers/pass vs ~20).
__global__ __launch_bounds__(256) void k_sel(const double* __restrict__ pooled,
                                             const float* __restrict__ fc_w,
                                             const float* __restrict__ fc_b,
                                             const float* __restrict__ w2,
                                             const float* __restrict__ w3,
                                             const double* __restrict__ spart,
                                             float* __restrict__ vector,
                                             int* __restrict__ kidx,
                                             short* __restrict__ wt2c,
                                             short* __restrict__ w3c,
                                             float* __restrict__ mask,
                                             float* __restrict__ mdil) {
    int role = blockIdx.x >> 6;
    int b = blockIdx.x & 63;
    int tid = threadIdx.x;

    // spmask LDS
    __shared__ unsigned long long ks[HW];
    __shared__ float m[HW];
    __shared__ unsigned int hist[256];
    __shared__ unsigned int wsum[4];
    __shared__ unsigned long long sh_prefix;
    __shared__ unsigned int sh_krem;
    // changather LDS
    __shared__ double ps[CIN];
    __shared__ double ss[WIDTH];
    __shared__ double kth;
    __shared__ int ki[K_CH];

    if (role == 1) {
        // ----- channel saliency + top-K_CH + compacted weight gather (f32 -> bf16 on the fly) -----
        for (int i = tid; i < CIN; i += 256) ps[i] = pooled[b * CIN + i];
        __syncthreads();
        if (tid < 64) {
            double acc = (double)fc_b[tid];
            const float* wr = fc_w + tid * CIN;
            for (int k = 0; k < CIN; k++) acc += ps[k] * (double)wr[k];
            ss[tid] = 1.0 / (1.0 + exp(-acc));
        }
        __syncthreads();
        if (tid < 64) {
            double sal = ss[tid];
            int cg = 0, ce = 0;
            for (int i = 0; i < WIDTH; i++) {
                cg += (ss[i] > sal);
                ce += (ss[i] == sal);
            }
            if (cg <= K_CH - 1 && cg + ce >= K_CH) kth = sal;
        }
        __syncthreads();
        if (tid < 64) {
            double sal = ss[tid];
            int kept = (sal >= kth) ? 1 : 0;
            vector[b * WIDTH + tid] = (float)kept;
            int pos = 0;
            for (int i = 0; i < tid; i++) pos += (ss[i] >= kth) ? 1 : 0;
            if (kept && pos < K_CH) { kidx[b * K_CH + pos] = tid; ki[pos] = tid; }
        }
        __syncthreads();
        for (int i = tid; i < 9216; i += 256) {
            int tap = i >> 10, rem = i & 1023;
            int oc_c = rem >> 5, c_c = rem & 31;
            wt2c[(size_t)b * 9216 + i] = (short)f2bf(w2[ki[oc_c] * 576 + ki[c_c] * 9 + tap]);
        }
        for (int i = tid; i < 8192; i += 256) {
            int oc = i >> 5, c_c = i & 31;
            w3c[(size_t)b * 8192 + i] = (short)f2bf(w3[oc * 64 + ki[c_c]]);
        }
        return;
    }

    // ----- spatial kth via EXACT 64-bit radix-select + mask + 3x3 dilate -----
#pragma unroll
    for (int i = 0; i < 13; i++) {
        int px = i * 256 + tid;
        if (px < HW) {
            double s = 0.0;
#pragma unroll
            for (int t = 0; t < 16; t++) s += spart[((size_t)(b * 16 + t)) * HW + px];
            unsigned long long u = __builtin_bit_cast(unsigned long long, s);
            ks[px] = (u >> 63) ? ~u : (u | 0x8000000000000000ULL);
        }
    }
    if (tid == 0) { sh_prefix = 0ULL; sh_krem = K_SP; }
    __syncthreads();

    unsigned long long pmask = 0ULL;
    for (int pass = 0; pass < 8; pass++) {
        int shift = 56 - 8 * pass;
        hist[tid] = 0;
        __syncthreads();
        unsigned long long prefix = sh_prefix;
#pragma unroll
        for (int i = 0; i < 13; i++) {
            int px = i * 256 + tid;
            if (px < HW) {
                unsigned long long k = ks[px];
                if ((k & pmask) == prefix)
                    atomicAdd(&hist[(unsigned)((k >> shift) & 255ULL)], 1u);
            }
        }
        __syncthreads();
        // cumulative count of digits >= d (d = 255 - tid), via wave-level inclusive scan
        unsigned hval = hist[255 - tid];
        unsigned v = hval;
#pragma unroll
        for (int off2 = 1; off2 < 64; off2 <<= 1) {
            unsigned n = __shfl_up(v, off2, 64);
            if ((tid & 63) >= off2) v += n;
        }
        if ((tid & 63) == 63) wsum[tid >> 6] = v;
        __syncthreads();
        unsigned add = 0;
#pragma unroll
        for (int k2 = 0; k2 < 3; k2++) if ((tid >> 6) > k2) add += wsum[k2];
        v += add;
        unsigned krem = sh_krem;
        unsigned cum = v;             // count of keys with digit >= d (given prefix)
        unsigned cumHigher = v - hval; // digit > d
        __syncthreads();
        if (cum >= krem && cumHigher < krem) {
            int d = 255 - tid;
            sh_krem = krem - cumHigher;
            sh_prefix = prefix | ((unsigned long long)d << shift);
        }
        pmask |= (0xFFULL << shift);
        __syncthreads();
    }
    unsigned long long kthk = sh_prefix;

#pragma unroll
    for (int i = 0; i < 13; i++) {
        int px = i * 256 + tid;
        if (px < HW) {
            float mv = (ks[px] >= kthk) ? 1.0f : 0.0f;
            m[px] = mv;
            mask[b * HW + px] = mv;
        }
    }
    __syncthreads();
    for (int p = tid; p < HW; p += 256) {
        int y = p / WW, xx = p % WW;
        float mx = 0.0f;
        for (int dy = -1; dy <= 1; dy++) {
            int yy = y + dy;
            if (yy < 0 || yy >= HH) continue;
            for (int dx = -1; dx <= 1; dx++) {
                int xc = xx + dx;
                if (xc < 0 || xc >= WW) continue;
                mx = fmaxf(mx, m[yy * WW + xc]);
            }
        }
        mdil[b * HW + p] = mx;
    }
}

// ---------------- Kernel 5: conv1 1x1 (256->32 kept) LDS-FREE direct-global MFMA (f32 weights) ----------------
__global__ __launch_bounds__(256, 2) void k_conv1(const float* __restrict__ x,
                                                  const float* __restrict__ w1,
                                                  const float* __restrict__ g1, const float* __restrict__ b1,
                                                  const float* __restrict__ m1, const float* __restrict__ v1,
                                                  const float* __restrict__ mdil,
                                                  const int* __restrict__ kidx,
                                                  short* __restrict__ out1c) {
    __shared__ float scc[32], shc[32];
    __shared__ int ki[32];
    int b = blockIdx.y, p0 = blockIdx.x * 448;
    int tid = threadIdx.x, w = tid >> 6, lane = tid & 63, g = lane >> 4, ln = lane & 15;
    if (tid < 32) {
        int c = kidx[b * K_CH + tid];
        ki[tid] = c;
        float s = g1[c] * rsqrtf(v1[c] + EPS);
        scc[tid] = s; shc[tid] = b1[c] - m1[c] * s;
    }
    __syncthreads();

    int pxw = p0 + w * 112 + ln;
    f32x4 acc[2][7];
    f32x4 zz = {0.f, 0.f, 0.f, 0.f};
#pragma unroll
    for (int m = 0; m < 2; m++)
#pragma unroll
        for (int nt = 0; nt < 7; nt++) acc[m][nt] = zz;

#pragma unroll
    for (int ks = 0; ks < 8; ks++) {
        short8 afr[2];
#pragma unroll
        for (int m = 0; m < 2; m++) {
            const float* wp = w1 + (ki[m * 16 + ln] * 256 + ks * 32 + g * 8);
            f32x4 a0 = *(const f32x4*)(wp);
            f32x4 a1 = *(const f32x4*)(wp + 4);
#pragma unroll
            for (int j = 0; j < 4; j++) {
                afr[m][j]     = (short)f2bf(a0[j]);
                afr[m][4 + j] = (short)f2bf(a1[j]);
            }
        }
        const float* xp0 = x + ((size_t)(b * 256 + ks * 32 + g * 8)) * HW + pxw;
#pragma unroll
        for (int nt = 0; nt < 7; nt++) {
            const float* xp = xp0 + nt * 16;
            short8 bfr;
#pragma unroll
            for (int j = 0; j < 8; j++)
                bfr[j] = (short)f2bf(xp[(size_t)j * HW]);
#pragma unroll
            for (int m = 0; m < 2; m++) acc[m][nt] = MFMA16(afr[m], bfr, acc[m][nt]);
        }
    }
#pragma unroll
    for (int nt = 0; nt < 7; nt++) {
        int px = pxw + nt * 16;
        float md = mdil[b * HW + px];
#pragma unroll
        for (int m = 0; m < 2; m++) {
            int oc = m * 16 + g * 4;
            float y0 = fmaxf(acc[m][nt][0] * scc[oc + 0] + shc[oc + 0], 0.f) * md;
            float y1 = fmaxf(acc[m][nt][1] * scc[oc + 1] + shc[oc + 1], 0.f) * md;
            float y2 = fmaxf(acc[m][nt][2] * scc[oc + 2] + shc[oc + 2], 0.f) * md;
            float y3 = fmaxf(acc[m][nt][3] * scc[oc + 3] + shc[oc + 3], 0.f) * md;
            uint2 u;
            u.x = (unsigned)f2bf(y0) | ((unsigned)f2bf(y1) << 16);
            u.y = (unsigned)f2bf(y2) | ((unsigned)f2bf(y3) << 16);
            *(uint2*)(out1c + ((size_t)(b * HW + px)) * 32 + oc) = u;
        }
    }
}

// ---------------- Kernel 6: conv2 3x3 (32->32 kept), 4-row tiles / 128 thr for load balance ----------------
__global__ __launch_bounds__(128, 2) void k_conv2(const short* __restrict__ out1c,
                                                  const short* __restrict__ wt2c,
                                                  const float* __restrict__ g2, const float* __restrict__ b2,
                                                  const float* __restrict__ m2, const float* __restrict__ v2,
                                                  const float* __restrict__ mask,
                                                  const int* __restrict__ kidx,
                                                  short* __restrict__ out2c) {
    __shared__ short lds[6 * 58 * 32];   // 22272 B
    __shared__ float scc[32], shc[32];
    int b = blockIdx.y, r0 = blockIdx.x * 4, p0 = r0 * 56;
    int tid = threadIdx.x, w = tid >> 6, lane = tid & 63, g = lane >> 4, ln = lane & 15;
    if (tid < 32) {
        int c = kidx[b * K_CH + tid];
        float s = g2[c] * rsqrtf(v2[c] + EPS);
        scc[tid] = s; shc[tid] = b2[c] - m2[c] * s;
    }
    short8 z8 = {0, 0, 0, 0, 0, 0, 0, 0};
    for (int i = tid; i < 1392; i += 128) {
        int cblk = i & 3;
        int colr = i >> 2;
        int col = colr % 58, ri = colr / 58;
        int gr = r0 - 1 + ri, gc = col - 1;
        short8 v8 = z8;
        if (gr >= 0 && gr < HH && gc >= 0 && gc < WW)
            v8 = *(const short8*)(out1c + ((size_t)(b * HW + gr * WW + gc)) * 32 + cblk * 8);
        *(short8*)(&lds[(ri * 58 + col) * 32 + ((cblk * 8) ^ ((col & 3) << 3))]) = v8;
    }
    __syncthreads();

    f32x4 acc[2][7];
    f32x4 zz = {0.f, 0.f, 0.f, 0.f};
#pragma unroll
    for (int m = 0; m < 2; m++)
#pragma unroll
        for (int nt = 0; nt < 7; nt++) acc[m][nt] = zz;

    const short* wtb = wt2c + (size_t)b * 9216;
    int prel0 = w * 112 + ln;
    for (int tap = 0; tap < 9; tap++) {
        int dy = tap / 3 - 1;
        int dx = tap - (tap / 3) * 3 - 1;
        short8 afr[2];
#pragma unroll
        for (int m = 0; m < 2; m++)
            afr[m] = *(const short8*)(wtb + tap * 1024 + (m * 16 + ln) * 32 + g * 8);
#pragma unroll
        for (int nt = 0; nt < 7; nt++) {
            int prel = prel0 + nt * 16;
            int rrel = prel / 56;
            int xcol = prel - rrel * 56;
            int row_l = rrel + 1 + dy;
            int col_l = xcol + 1 + dx;
            short8 bfr = *(const short8*)(&lds[(row_l * 58 + col_l) * 32 + ((g * 8) ^ ((col_l & 3) << 3))]);
#pragma unroll
            for (int m = 0; m < 2; m++) acc[m][nt] = MFMA16(afr[m], bfr, acc[m][nt]);
        }
    }
#pragma unroll
    for (int nt = 0; nt < 7; nt++) {
        int px = p0 + prel0 + nt * 16;
        float mv = mask[b * HW + px];
#pragma unroll
        for (int m = 0; m < 2; m++) {
            int oc = m * 16 + g * 4;
            float y0 = fmaxf(acc[m][nt][0] * scc[oc + 0] + shc[oc + 0], 0.f) * mv;
            float y1 = fmaxf(acc[m][nt][1] * scc[oc + 1] + shc[oc + 1], 0.f) * mv;
            float y2 = fmaxf(acc[m][nt][2] * scc[oc + 2] + shc[oc + 2], 0.f) * mv;
            float y3 = fmaxf(acc[m][nt][3] * scc[oc + 3] + shc[oc + 3], 0.f) * mv;
            uint2 u;
            u.x = (unsigned)f2bf(y0) | ((unsigned)f2bf(y1) << 16);
            u.y = (unsigned)f2bf(y2) | ((unsigned)f2bf(y3) << 16);
            *(uint2*)(out2c + ((size_t)(b * HW + px)) * 32 + oc) = u;
        }
    }
}

// ---------------- Kernel 7: conv3 1x1 (32 kept ->256), 16-oc waves for 4 waves/SIMD occupancy ----------------
__global__ __launch_bounds__(256, 4) void k_conv3(const short* __restrict__ out2c,
                                                  const short* __restrict__ w3c,
                                                  const float* __restrict__ g3, const float* __restrict__ b3,
                                                  const float* __restrict__ m3, const float* __restrict__ v3,
                                                  const float* __restrict__ mask,
                                                  const float* __restrict__ x,
                                                  float* __restrict__ out) {
    int b = blockIdx.y;
    int ocb = blockIdx.x / 28;          // 0..3
    int pxb = blockIdx.x % 28;          // 0..27
    int p0 = pxb * 112;
    int tid = threadIdx.x, w = tid >> 6, lane = tid & 63, g = lane >> 4, ln = lane & 15;
    int oc0 = ocb * 64 + w * 16;
    int oc = oc0 + ln;

    const short* w3b = w3c + (size_t)b * 8192;
    short8 wfr = *(const short8*)(w3b + oc * 32 + g * 8);

    short8 act[7];
#pragma unroll
    for (int nt = 0; nt < 7; nt++)
        act[nt] = *(const short8*)(out2c + ((size_t)(b * HW + p0 + nt * 16 + ln)) * 32 + g * 8);

    f32x4 xr[7];
#pragma unroll
    for (int nt = 0; nt < 7; nt++) {
        int px0 = p0 + nt * 16 + g * 4;
        xr[nt] = *(const f32x4*)(x + ((size_t)(b * COUT + oc)) * HW + px0);
    }
    __builtin_amdgcn_sched_barrier(0);

    f32x4 acc[7];
    f32x4 zz = {0.f, 0.f, 0.f, 0.f};
#pragma unroll
    for (int nt = 0; nt < 7; nt++) acc[nt] = zz;
#pragma unroll
    for (int nt = 0; nt < 7; nt++)
        acc[nt] = MFMA16(act[nt], wfr, acc[nt]);

    float s_ = g3[oc] * rsqrtf(v3[oc] + EPS);
    float h_ = b3[oc] - m3[oc] * s_;
#pragma unroll
    for (int nt = 0; nt < 7; nt++) {
        int px0 = p0 + nt * 16 + g * 4;
        f32x4 mv = *(const f32x4*)(mask + (size_t)b * HW + px0);
        size_t idx = ((size_t)(b * COUT + oc)) * HW + px0;
        f32x4 o;
#pragma unroll
        for (int i = 0; i < 4; i++)
            o[i] = fmaxf(xr[nt][i] + (acc[nt][i] * s_ + h_) * mv[i], 0.f);
        *(f32x4*)(out + idx) = o;
    }
}

extern "C" void kernel_launch(void* const* d_in, const int* in_sizes, int n_in,
                              void* d_out, int out_size, void* d_ws, size_t ws_size,
                              hipStream_t stream) {
    const float* x       = (const float*)d_in[0];
    const float* conv1_w = (const float*)d_in[1];
    const float* bn1_g   = (const float*)d_in[2];
    const float* bn1_b   = (const float*)d_in[3];
    const float* bn1_m   = (const float*)d_in[4];
    const float* bn1_v   = (const float*)d_in[5];
    const float* conv2_w = (const float*)d_in[6];
    const float* bn2_g   = (const float*)d_in[7];
    const float* bn2_b   = (const float*)d_in[8];
    const float* bn2_m   = (const float*)d_in[9];
    const float* bn2_v   = (const float*)d_in[10];
    const float* conv3_w = (const float*)d_in[11];
    const float* bn3_g   = (const float*)d_in[12];
    const float* bn3_b   = (const float*)d_in[13];
    const float* bn3_m   = (const float*)d_in[14];
    const float* bn3_v   = (const float*)d_in[15];
    const float* fc_w    = (const float*)d_in[16];
    const float* fc_b    = (const float*)d_in[17];
    const float* mask_w  = (const float*)d_in[18];
    const float* mask_b  = (const float*)d_in[19];
    (void)mask_b;   // constant bias cancels in (sal >= kth)

    char* wsb = (char*)d_ws;
    size_t off = 0;
    double* pooled = (double*)(wsb + off); off += (size_t)BATCH * CIN * 8;        // 128 KB
    double* spart  = (double*)(wsb + off); off += (size_t)BATCH * 16 * HW * 8;    // 25.7 MB
    float* vector  = (float*)(wsb + off);  off += (size_t)BATCH * WIDTH * 4;
    float* mask    = (float*)(wsb + off);  off += (size_t)BATCH * HW * 4;
    float* mdil    = (float*)(wsb + off);  off += (size_t)BATCH * HW * 4;
    int*   kidx    = (int*)(wsb + off);    off += (size_t)BATCH * K_CH * 4;
    short* wt2c    = (short*)(wsb + off);  off += (size_t)BATCH * 9216 * 2;       // 1.18 MB
    short* w3c     = (short*)(wsb + off);  off += (size_t)BATCH * 8192 * 2;       // 1.05 MB
    short* out1c   = (short*)(wsb + off);  off += (size_t)BATCH * HW * 32 * 2;    // 12.8 MB
    short* out2c   = (short*)(wsb + off);  off += (size_t)BATCH * HW * 32 * 2;    // 12.8 MB
    (void)ws_size; (void)in_sizes; (void)n_in; (void)out_size; (void)vector;

    k_poolsal<<<dim3(16, BATCH), 256, 0, stream>>>(x, mask_w, pooled, spart);
    k_sel<<<128, 256, 0, stream>>>(pooled, fc_w, fc_b, conv2_w, conv3_w, spart,
                                   vector, kidx, wt2c, w3c, mask, mdil);
    k_conv1<<<dim3(7, BATCH), 256, 0, stream>>>(x, conv1_w, bn1_g, bn1_b, bn1_m, bn1_v, mdil, kidx, out1c);
    k_conv2<<<dim3(14, BATCH), 128, 0, stream>>>(out1c, wt2c, bn2_g, bn2_b, bn2_m, bn2_v, mask, kidx, out2c);
    k_conv3<<<dim3(112, BATCH), 256, 0, stream>>>(out2c, w3c, bn3_g, bn3_b, bn3_m, bn3_v, mask, x, (float*)d_out);
}